// Round 6
// baseline (206.045 us; speedup 1.0000x reference)
//
#include <hip/hip_runtime.h>

// Shapes: x[2,16,1024,512] f32, past_kv[2,16,64,64] f32, Wq/Wk/Wv[64,512], b*[64]
// Outputs (concat): out [2,16,1024,64] (group-normed), current_kv [2,16,1024,64,64]

constexpr int B  = 2;
constexpr int NH = 16;
constexpr int L  = 1024;
constexpr int E  = 512;
constexpr int D  = 64;
constexpr int M  = B * NH * L;     // 32768 rows
constexpr int NQKV = 192;
constexpr int BLK = 64;            // positions per fused block
constexpr int NBLKS = M / BLK;     // 512
constexpr float EPS = 1e-5f;

using short8 = __attribute__((ext_vector_type(8))) short;
using f32x4  = __attribute__((ext_vector_type(4))) float;

__device__ __forceinline__ unsigned short f2bf(float f) {
    union { float f; unsigned int u; } x; x.f = f;
    unsigned int u = x.u;
    return (unsigned short)((u + 0x7fffu + ((u >> 16) & 1u)) >> 16);
}
__device__ __forceinline__ float bf2f(unsigned short h) {
    union { unsigned int u; float f; } x; x.u = ((unsigned int)h) << 16;
    return x.f;
}

// ---------------------------------------------------------------------------
// Kernel 0: convert Wq|Wk|Wv (each 64x512 f32) -> Wb bf16 [192][512] (in ws)
// ---------------------------------------------------------------------------
__global__ __launch_bounds__(256) void convw_kernel(
    const float* __restrict__ Wq, const float* __restrict__ Wk,
    const float* __restrict__ Wv, unsigned short* __restrict__ Wb)
{
    int idx = blockIdx.x * 256 + threadIdx.x;      // float4 index, 0..24575
    const float* src = (idx < 8192) ? Wq : (idx < 16384) ? Wk : Wv;
    int off = idx & 8191;
    float4 v = ((const float4*)src)[off];
    Wb[(size_t)idx * 4 + 0] = f2bf(v.x);
    Wb[(size_t)idx * 4 + 1] = f2bf(v.y);
    Wb[(size_t)idx * 4 + 2] = f2bf(v.z);
    Wb[(size_t)idx * 4 + 3] = f2bf(v.w);
}

// ---------------------------------------------------------------------------
// Kernel 1: FUSED proj + retention. 512 blocks x 256 threads (4 waves).
// Block = 64 consecutive positions of one head (16 blocks per (b,n)).
//  phase 1: qkv[64][192] = X[64][512] @ Wb^T + bias  (MFMA, W staged in LDS)
//  phase 2: qkv -> LDS bf16 (overlays proj staging)
//  phase 3: ckv = decay*pkv + k (x) v  (1 MB contiguous stores per block)
//  phase 4: out_pre = decay*(q@pkv) + (q.k)*v; block groupnorm partials
// LDS ~53.5 KB -> 2 blocks/CU: block A's MFMA overlaps block B's store drain.
// ---------------------------------------------------------------------------
__global__ __launch_bounds__(256) void fused_kernel(
    const float* __restrict__ x,
    const unsigned short* __restrict__ Wb,   // [192][512] bf16
    const float* __restrict__ bq, const float* __restrict__ bk,
    const float* __restrict__ bv,
    const float* __restrict__ past_kv,       // [B*NH, 64, 64]
    float* __restrict__ out_pre,             // [M,64]
    float* __restrict__ ckv,                 // [M,4096]
    float* __restrict__ partials)            // [NBLKS,2]
{
    constexpr int LDP = 72;    // proj staging pad (ushorts)
    constexpr int QSP = 200;   // qkv row stride (ushorts), 400B (8B-aligned)
    // proj staging (36.8 KB) overlaid later by qs[64][200] (25.6 KB)
    __shared__ __align__(16) unsigned char smem[(64 * LDP + 192 * LDP) * 2];
    auto Xs = (unsigned short(*)[LDP])smem;                       // [64][72]
    auto Ws = (unsigned short(*)[LDP])(smem + 64 * LDP * 2);      // [192][72]
    auto qs = (unsigned short(*)[QSP])smem;                       // [64][200]
    __shared__ float pkv_s[64 * 64];   // 16 KB
    __shared__ float qk_s[BLK];
    __shared__ float red[8];

    const int blk  = blockIdx.x;
    const int bn   = blk >> 4;              // 16 blocks per (b,n)
    const int pos0 = (blk & 15) * BLK;
    const int h    = bn & (NH - 1);
    const int tid  = threadIdx.x;
    const float decay = 1.0f - exp2f(-5.0f - (float)h);

    // ---- stage past_kv: regs (store slots) + LDS (out phase) ----
    const float* pkv = past_kv + (size_t)bn * 4096;
    float4 p4[4];
    #pragma unroll
    for (int j = 0; j < 4; ++j) {
        p4[j] = *(const float4*)&pkv[(tid + j * 256) * 4];
        *(float4*)&pkv_s[(tid + j * 256) * 4] = p4[j];
    }

    // ---- phase 1: projection MFMA ----
    const int wid  = tid >> 6;              // 0..3 -> col block of 48
    const int lane = tid & 63;
    const int l15  = lane & 15;
    const int lk   = (lane >> 4) * 8;

    const float* xrow = x + (size_t)(bn * L + pos0) * E;
    f32x4 acc[4][3] = {};

    for (int k0 = 0; k0 < E; k0 += 64) {
        // loads to regs first (latency overlap with prev MFMA of other waves)
        float4 xa[4];
        #pragma unroll
        for (int j = 0; j < 4; ++j) {
            int f = tid + j * 256;          // 0..1023: row=f>>4, c4=f&15
            xa[j] = *(const float4*)&xrow[(size_t)(f >> 4) * E + k0 + (f & 15) * 4];
        }
        short8 wch[6];
        #pragma unroll
        for (int j = 0; j < 6; ++j) {
            int c = tid + j * 256;          // 0..1535: wrow=c>>3, wc8=(c&7)*8
            wch[j] = *(const short8*)&Wb[(size_t)(c >> 3) * E + k0 + (c & 7) * 8];
        }
        __syncthreads();   // previous tile fully consumed
        #pragma unroll
        for (int j = 0; j < 4; ++j) {
            int f = tid + j * 256;
            unsigned short t4[4] = {f2bf(xa[j].x), f2bf(xa[j].y),
                                    f2bf(xa[j].z), f2bf(xa[j].w)};
            *(uint2*)&Xs[f >> 4][(f & 15) * 4] = *(uint2*)t4;
        }
        #pragma unroll
        for (int j = 0; j < 6; ++j) {
            int c = tid + j * 256;
            *(short8*)&Ws[c >> 3][(c & 7) * 8] = wch[j];
        }
        __syncthreads();

        #pragma unroll
        for (int kk = 0; kk < 2; ++kk) {
            short8 a[4], b[3];
            #pragma unroll
            for (int mi = 0; mi < 4; ++mi)
                a[mi] = *(const short8*)&Xs[mi * 16 + l15][kk * 32 + lk];
            #pragma unroll
            for (int ni = 0; ni < 3; ++ni)
                b[ni] = *(const short8*)&Ws[wid * 48 + ni * 16 + l15][kk * 32 + lk];
            #pragma unroll
            for (int mi = 0; mi < 4; ++mi)
                #pragma unroll
                for (int ni = 0; ni < 3; ++ni)
                    acc[mi][ni] = __builtin_amdgcn_mfma_f32_16x16x32_bf16(
                        a[mi], b[ni], acc[mi][ni], 0, 0, 0);
        }
    }
    __syncthreads();   // all MFMA LDS reads done; safe to overlay with qs

    // ---- phase 2: acc -> qs (bf16), + bias ----
    #pragma unroll
    for (int ni = 0; ni < 3; ++ni) {
        int col = wid * 48 + ni * 16 + l15;
        float bb = (col < 64) ? bq[col] : (col < 128) ? bk[col - 64] : bv[col - 128];
        #pragma unroll
        for (int mi = 0; mi < 4; ++mi) {
            #pragma unroll
            for (int j = 0; j < 4; ++j) {
                int row = mi * 16 + (lane >> 4) * 4 + j;
                qs[row][col] = f2bf(acc[mi][ni][j] + bb);
            }
        }
    }
    __syncthreads();

    // ---- q.k per position: pos = tid>>2, chunk c = tid&3 (16 elems) ----
    {
        int pos = tid >> 2, c = tid & 3;
        float p = 0.0f;
        #pragma unroll
        for (int j = 0; j < 16; ++j) {
            int e = c * 16 + j;
            p = fmaf(bf2f(qs[pos][e]), bf2f(qs[pos][64 + e]), p);
        }
        p += __shfl_xor(p, 1); p += __shfl_xor(p, 2);
        if (c == 0) qk_s[pos] = p;
    }
    __syncthreads();

    // ---- phase 3: ckv stores, 64 pos x 16 KB contiguous ----
    float* co = ckv + (size_t)(bn * L + pos0) * 4096;
    for (int pos = 0; pos < BLK; ++pos) {
        const unsigned short* ks = &qs[pos][64];
        const unsigned short* vs = &qs[pos][128];
        #pragma unroll
        for (int j = 0; j < 4; ++j) {
            int f = tid + j * 256;           // float4 slot 0..1023
            float kk = bf2f(ks[f >> 4]);
            const unsigned short* vp = &vs[(f & 15) * 4];
            float4 r;
            r.x = fmaf(decay, p4[j].x, kk * bf2f(vp[0]));
            r.y = fmaf(decay, p4[j].y, kk * bf2f(vp[1]));
            r.z = fmaf(decay, p4[j].z, kk * bf2f(vp[2]));
            r.w = fmaf(decay, p4[j].w, kk * bf2f(vp[3]));
            *(float4*)&co[(size_t)pos * 4096 + f * 4] = r;
        }
    }

    // ---- phase 4: out. wave w -> pos = w + pp*4 (16 pos), vd = lane ----
    const int vd = lane;
    float accs[16] = {};
    for (int kd = 0; kd < 64; ++kd) {
        float pv = pkv_s[kd * 64 + vd];
        #pragma unroll
        for (int pp = 0; pp < 16; ++pp)
            accs[pp] = fmaf(bf2f(qs[wid + pp * 4][kd]), pv, accs[pp]);
    }
    float s1 = 0.0f, s2 = 0.0f;
    #pragma unroll
    for (int pp = 0; pp < 16; ++pp) {
        int pos = wid + pp * 4;
        float o = fmaf(decay, accs[pp], qk_s[pos] * bf2f(qs[pos][128 + vd]));
        out_pre[(size_t)(bn * L + pos0 + pos) * D + vd] = o;
        s1 += o; s2 += o * o;
    }

    // ---- block partials ----
    #pragma unroll
    for (int off = 32; off; off >>= 1) {
        s1 += __shfl_down(s1, off);
        s2 += __shfl_down(s2, off);
    }
    if (lane == 0) { red[wid * 2] = s1; red[wid * 2 + 1] = s2; }
    __syncthreads();
    if (tid == 0) {
        float a = 0.0f, b2 = 0.0f;
        #pragma unroll
        for (int w = 0; w < 4; ++w) { a += red[w * 2]; b2 += red[w * 2 + 1]; }
        partials[(size_t)blk * 2]     = a;
        partials[(size_t)blk * 2 + 1] = b2;
    }
}

// ---------------------------------------------------------------------------
// Kernel 2: per-group (b,n) reduction: 16 partials per group, one wave each
// ---------------------------------------------------------------------------
__global__ __launch_bounds__(64) void group_reduce_kernel(
    const float* __restrict__ partials, float* __restrict__ stats)
{
    const int g   = blockIdx.x;   // 0..31
    const int tid = threadIdx.x;  // 0..63
    float s1 = 0.0f, s2 = 0.0f;
    if (tid < 16) {
        s1 = partials[(size_t)(g * 16 + tid) * 2];
        s2 = partials[(size_t)(g * 16 + tid) * 2 + 1];
    }
    #pragma unroll
    for (int off = 8; off; off >>= 1) {
        s1 += __shfl_down(s1, off);
        s2 += __shfl_down(s2, off);
    }
    if (tid == 0) {
        const float cnt = (float)(L * D);
        float mean = s1 / cnt;
        float var  = s2 / cnt - mean * mean;
        stats[g * 2]     = mean;
        stats[g * 2 + 1] = rsqrtf(var + EPS);
    }
}

// ---------------------------------------------------------------------------
// Kernel 3: in-place normalize (float4)
// ---------------------------------------------------------------------------
__global__ __launch_bounds__(256) void normalize_kernel(
    float* __restrict__ out, const float* __restrict__ stats)
{
    int idx = blockIdx.x * 256 + threadIdx.x;   // float4 index
    int g = idx >> 14;                          // 16384 float4 per group
    float mean = stats[g * 2];
    float rstd = stats[g * 2 + 1];
    float4 v = ((const float4*)out)[idx];
    v.x = (v.x - mean) * rstd; v.y = (v.y - mean) * rstd;
    v.z = (v.z - mean) * rstd; v.w = (v.w - mean) * rstd;
    ((float4*)out)[idx] = v;
}

// ---------------------------------------------------------------------------
extern "C" void kernel_launch(void* const* d_in, const int* in_sizes, int n_in,
                              void* d_out, int out_size, void* d_ws, size_t ws_size,
                              hipStream_t stream)
{
    const float* x       = (const float*)d_in[0];
    const float* past_kv = (const float*)d_in[1];
    const float* Wq      = (const float*)d_in[2];
    const float* bq      = (const float*)d_in[3];
    const float* Wk      = (const float*)d_in[4];
    const float* bk      = (const float*)d_in[5];
    const float* Wv      = (const float*)d_in[6];
    const float* bv      = (const float*)d_in[7];

    float* out = (float*)d_out;                    // [M*64]
    float* ckv = out + (size_t)M * 64;             // [M*4096]

    unsigned short* Wb = (unsigned short*)d_ws;            // 192*512 bf16
    float* partials = (float*)(Wb + (size_t)NQKV * E);     // NBLKS*2
    float* stats    = partials + (size_t)NBLKS * 2;        // 64

    convw_kernel<<<96, 256, 0, stream>>>(Wq, Wk, Wv, Wb);
    fused_kernel<<<NBLKS, 256, 0, stream>>>(x, Wb, bq, bk, bv, past_kv,
                                            out, ckv, partials);
    group_reduce_kernel<<<32, 64, 0, stream>>>(partials, stats);
    normalize_kernel<<<(M * 16) / 256, 256, 0, stream>>>(out, stats);
}

// Round 8
// 137.914 us; speedup vs baseline: 1.4940x; 1.4940x over previous
//
#include <hip/hip_runtime.h>

// Shapes: x[2,16,1024,512] f32, past_kv[2,16,64,64] f32, Wq/Wk/Wv[64,512], b*[64]
// Outputs (concat): out [2,16,1024,64] (group-normed), current_kv [2,16,1024,64,64]

constexpr int B  = 2;
constexpr int NH = 16;
constexpr int L  = 1024;
constexpr int E  = 512;
constexpr int D  = 64;
constexpr int M  = B * NH * L;     // 32768 rows
constexpr int NQKV = 192;
constexpr int BLK = 32;            // positions per retention block
constexpr int NBLKS = M / BLK;     // 1024
constexpr float EPS = 1e-5f;

using short8 = __attribute__((ext_vector_type(8))) short;
using f32x4  = __attribute__((ext_vector_type(4))) float;

__device__ __forceinline__ unsigned short f2bf(float f) {
    union { float f; unsigned int u; } x; x.f = f;
    unsigned int u = x.u;
    return (unsigned short)((u + 0x7fffu + ((u >> 16) & 1u)) >> 16);
}
__device__ __forceinline__ float bf2f(unsigned short h) {
    union { unsigned int u; float f; } x; x.u = ((unsigned int)h) << 16;
    return x.f;
}

// ---------------------------------------------------------------------------
// Kernel 0: convert Wq|Wk|Wv (each 64x512 f32) -> Wb bf16 [192][512] (in ws)
// ---------------------------------------------------------------------------
__global__ __launch_bounds__(256) void convw_kernel(
    const float* __restrict__ Wq, const float* __restrict__ Wk,
    const float* __restrict__ Wv, unsigned short* __restrict__ Wb)
{
    int idx = blockIdx.x * 256 + threadIdx.x;      // float4 index, 0..24575
    const float* src = (idx < 8192) ? Wq : (idx < 16384) ? Wk : Wv;
    int off = idx & 8191;
    float4 v = ((const float4*)src)[off];
    Wb[(size_t)idx * 4 + 0] = f2bf(v.x);
    Wb[(size_t)idx * 4 + 1] = f2bf(v.y);
    Wb[(size_t)idx * 4 + 2] = f2bf(v.z);
    Wb[(size_t)idx * 4 + 3] = f2bf(v.w);
}

// ---------------------------------------------------------------------------
// Kernel 1: QKV projection via bf16 MFMA -> bf16 qkv.
// BM=64 -> 512 blocks (2/CU, 16 waves/CU). BN=192(all), BK=64.
// 512 threads = 8 waves (2 row-halves x 4 col-blocks), each wave 32x48.
// ---------------------------------------------------------------------------
__global__ __launch_bounds__(512) void proj_mfma_kernel(
    const float* __restrict__ x, const unsigned short* __restrict__ Wb,
    const float* __restrict__ bq, const float* __restrict__ bk,
    const float* __restrict__ bv,
    unsigned short* __restrict__ qkvb)   // [M,192] bf16
{
    constexpr int BM = 64, BK = 64, LDP = 72;
    __shared__ unsigned short Xs[BM][LDP];      // 9.2 KB
    __shared__ unsigned short Ws[NQKV][LDP];    // 27.6 KB
    __shared__ float bias_s[NQKV];

    const int tid  = threadIdx.x;
    const int row0 = blockIdx.x * BM;
    if (tid < NQKV)
        bias_s[tid] = (tid < 64) ? bq[tid] : (tid < 128) ? bk[tid - 64] : bv[tid - 128];

    const int wid  = tid >> 6;
    const int lane = tid & 63;
    const int wr   = wid >> 2;            // 0..1 row half (32 rows)
    const int wc   = wid & 3;             // 0..3 col block (48 cols)
    const int l15  = lane & 15;
    const int lk   = (lane >> 4) * 8;

    f32x4 acc[2][3] = {};

    for (int k0 = 0; k0 < E; k0 += BK) {
        float4 xa[2];
        #pragma unroll
        for (int j = 0; j < 2; ++j) {
            int f = tid + j * 512;         // float4 slot 0..1023 (64 rows x 16)
            xa[j] = *(const float4*)&x[(size_t)(row0 + (f >> 4)) * E + k0 + (f & 15) * 4];
        }
        short8 wch[3];
        #pragma unroll
        for (int j = 0; j < 3; ++j) {
            int c = tid + j * 512;         // chunk 0..1535 (192 rows x 8)
            wch[j] = *(const short8*)&Wb[(size_t)(c >> 3) * E + k0 + (c & 7) * 8];
        }
        __syncthreads();   // previous tile fully consumed
        #pragma unroll
        for (int j = 0; j < 2; ++j) {
            int f = tid + j * 512;
            unsigned short t4[4] = {f2bf(xa[j].x), f2bf(xa[j].y),
                                    f2bf(xa[j].z), f2bf(xa[j].w)};
            *(uint2*)&Xs[f >> 4][(f & 15) * 4] = *(uint2*)t4;
        }
        #pragma unroll
        for (int j = 0; j < 3; ++j) {
            int c = tid + j * 512;
            *(short8*)&Ws[c >> 3][(c & 7) * 8] = wch[j];
        }
        __syncthreads();

        #pragma unroll
        for (int kk = 0; kk < 2; ++kk) {
            short8 a[2], b[3];
            #pragma unroll
            for (int mi = 0; mi < 2; ++mi)
                a[mi] = *(const short8*)&Xs[wr * 32 + mi * 16 + l15][kk * 32 + lk];
            #pragma unroll
            for (int ni = 0; ni < 3; ++ni)
                b[ni] = *(const short8*)&Ws[wc * 48 + ni * 16 + l15][kk * 32 + lk];
            #pragma unroll
            for (int mi = 0; mi < 2; ++mi)
                #pragma unroll
                for (int ni = 0; ni < 3; ++ni)
                    acc[mi][ni] = __builtin_amdgcn_mfma_f32_16x16x32_bf16(
                        a[mi], b[ni], acc[mi][ni], 0, 0, 0);
        }
    }

    #pragma unroll
    for (int mi = 0; mi < 2; ++mi) {
        #pragma unroll
        for (int ni = 0; ni < 3; ++ni) {
            int col = wc * 48 + ni * 16 + l15;
            float bb = bias_s[col];
            #pragma unroll
            for (int j = 0; j < 4; ++j) {
                int row = wr * 32 + mi * 16 + (lane >> 4) * 4 + j;
                qkvb[(size_t)(row0 + row) * NQKV + col] = f2bf(acc[mi][ni][j] + bb);
            }
        }
    }
}

// ---------------------------------------------------------------------------
// Kernel 2: fused retention, 32 positions / block, 512 threads, 1024 blocks.
//   4 blocks x 8 waves per CU = 32 waves/CU. Non-temporal ckv stores.
// ---------------------------------------------------------------------------
__global__ __launch_bounds__(512) void retention_kernel(
    const unsigned short* __restrict__ qkvb,  // [M,192] bf16
    const float* __restrict__ past_kv,        // [B*NH, 64, 64]
    float* __restrict__ out_pre,              // [M,64]
    float* __restrict__ ckv,                  // [M,4096]
    float* __restrict__ partials)             // [NBLKS,2]
{
    const int blk  = blockIdx.x;
    const int bn   = blk >> 5;             // 32 blocks per (b,n)
    const int pos0 = (blk & 31) * BLK;
    const int h    = bn & (NH - 1);
    const int tid  = threadIdx.x;
    const float decay = 1.0f - exp2f(-5.0f - (float)h);

    __shared__ float pkv_s[64 * 64];               // 16 KB
    __shared__ unsigned short qkv_s[BLK * NQKV];   // 12 KB
    __shared__ float qk_s[BLK];
    __shared__ float red[16];

    // ---- stage past_kv (keep this thread's store slots in regs too) ----
    const float* pkv = past_kv + (size_t)bn * 4096;
    float4 p4[2];
    #pragma unroll
    for (int j = 0; j < 2; ++j) {
        p4[j] = *(const float4*)&pkv[(tid + j * 512) * 4];
        *(float4*)&pkv_s[(tid + j * 512) * 4] = p4[j];
    }
    // ---- stage qkv rows (bf16): 32*192 ushorts = 768 uint4 ----
    const unsigned short* qrow = qkvb + (size_t)(bn * L + pos0) * NQKV;
    for (int f = tid; f < 768; f += 512)
        ((uint4*)qkv_s)[f] = ((const uint4*)qrow)[f];
    __syncthreads();

    // ---- q.k per position: pos = tid>>4, chunk c = tid&15 (4 elems) ----
    {
        int pos = tid >> 4, c = tid & 15;
        const unsigned short* qp = &qkv_s[pos * NQKV];
        float p = 0.0f;
        #pragma unroll
        for (int j = 0; j < 4; ++j)
            p = fmaf(bf2f(qp[c * 4 + j]), bf2f(qp[64 + c * 4 + j]), p);
        p += __shfl_xor(p, 1); p += __shfl_xor(p, 2);
        p += __shfl_xor(p, 4); p += __shfl_xor(p, 8);
        if (c == 0) qk_s[pos] = p;
    }

    // ---- ckv stores: 32 pos x 16 KB contiguous, NON-TEMPORAL ----
    // f = tid + j*512: (f&15) is j-invariant -> one v read per pos;
    // kd = f>>4 differs by 32 between j=0,1.
    float* co = ckv + (size_t)(bn * L + pos0) * 4096;
    const int kd0 = tid >> 4, vc = (tid & 15) * 4;
    #pragma unroll 2
    for (int pos = 0; pos < BLK; ++pos) {
        const unsigned short* ks = &qkv_s[pos * NQKV + 64];
        const unsigned short* vs = &qkv_s[pos * NQKV + 128];
        unsigned short vb[4];
        *(uint2*)vb = *(const uint2*)&vs[vc];
        float v0 = bf2f(vb[0]), v1 = bf2f(vb[1]),
              v2 = bf2f(vb[2]), v3 = bf2f(vb[3]);
        float kk0 = bf2f(ks[kd0]);
        float kk1 = bf2f(ks[kd0 + 32]);
        f32x4 r0, r1;
        r0.x = fmaf(decay, p4[0].x, kk0 * v0);
        r0.y = fmaf(decay, p4[0].y, kk0 * v1);
        r0.z = fmaf(decay, p4[0].z, kk0 * v2);
        r0.w = fmaf(decay, p4[0].w, kk0 * v3);
        r1.x = fmaf(decay, p4[1].x, kk1 * v0);
        r1.y = fmaf(decay, p4[1].y, kk1 * v1);
        r1.z = fmaf(decay, p4[1].z, kk1 * v2);
        r1.w = fmaf(decay, p4[1].w, kk1 * v3);
        __builtin_nontemporal_store(r0, (f32x4*)&co[(size_t)pos * 4096 + tid * 4]);
        __builtin_nontemporal_store(r1, (f32x4*)&co[(size_t)pos * 4096 + (tid + 512) * 4]);
    }
    __syncthreads();   // qk_s ready for all waves

    // ---- out: wave = tid>>6 (0..7), vd = tid&63; pos = wave + pp*8 ----
    const int wave = tid >> 6, lane = tid & 63;
    const int vd = lane;
    float accs[4] = {0.0f, 0.0f, 0.0f, 0.0f};
    for (int kd = 0; kd < 64; ++kd) {
        float pv = pkv_s[kd * 64 + vd];
        #pragma unroll
        for (int pp = 0; pp < 4; ++pp)
            accs[pp] = fmaf(bf2f(qkv_s[(wave + pp * 8) * NQKV + kd]), pv, accs[pp]);
    }
    float s1 = 0.0f, s2 = 0.0f;
    #pragma unroll
    for (int pp = 0; pp < 4; ++pp) {
        int pos = wave + pp * 8;
        float o = fmaf(decay, accs[pp],
                       qk_s[pos] * bf2f(qkv_s[pos * NQKV + 128 + vd]));
        out_pre[(size_t)(bn * L + pos0 + pos) * D + vd] = o;
        s1 += o; s2 += o * o;
    }

    // ---- block partials: wave shuffle-reduce, then 8-way LDS combine ----
    #pragma unroll
    for (int off = 32; off; off >>= 1) {
        s1 += __shfl_down(s1, off);
        s2 += __shfl_down(s2, off);
    }
    if (lane == 0) { red[wave * 2] = s1; red[wave * 2 + 1] = s2; }
    __syncthreads();
    if (tid == 0) {
        float a = 0.0f, b2 = 0.0f;
        #pragma unroll
        for (int w = 0; w < 8; ++w) { a += red[w * 2]; b2 += red[w * 2 + 1]; }
        partials[(size_t)blk * 2]     = a;
        partials[(size_t)blk * 2 + 1] = b2;
    }
}

// ---------------------------------------------------------------------------
// Kernel 3: per-group (b,n) reduction: 32 partials per group, one wave each
// ---------------------------------------------------------------------------
__global__ __launch_bounds__(64) void group_reduce_kernel(
    const float* __restrict__ partials, float* __restrict__ stats)
{
    const int g   = blockIdx.x;   // 0..31
    const int tid = threadIdx.x;  // 0..63
    float s1 = 0.0f, s2 = 0.0f;
    if (tid < 32) {
        s1 = partials[(size_t)(g * 32 + tid) * 2];
        s2 = partials[(size_t)(g * 32 + tid) * 2 + 1];
    }
    #pragma unroll
    for (int off = 16; off; off >>= 1) {
        s1 += __shfl_down(s1, off);
        s2 += __shfl_down(s2, off);
    }
    if (tid == 0) {
        const float cnt = (float)(L * D);
        float mean = s1 / cnt;
        float var  = s2 / cnt - mean * mean;
        stats[g * 2]     = mean;
        stats[g * 2 + 1] = rsqrtf(var + EPS);
    }
}

// ---------------------------------------------------------------------------
// Kernel 4: in-place normalize (float4, nt final store)
// ---------------------------------------------------------------------------
__global__ __launch_bounds__(256) void normalize_kernel(
    float* __restrict__ out, const float* __restrict__ stats)
{
    int idx = blockIdx.x * 256 + threadIdx.x;   // float4 index
    int g = idx >> 14;                          // 16384 float4 per group
    float mean = stats[g * 2];
    float rstd = stats[g * 2 + 1];
    f32x4 v = *((const f32x4*)out + idx);
    v.x = (v.x - mean) * rstd; v.y = (v.y - mean) * rstd;
    v.z = (v.z - mean) * rstd; v.w = (v.w - mean) * rstd;
    __builtin_nontemporal_store(v, (f32x4*)out + idx);
}

// ---------------------------------------------------------------------------
extern "C" void kernel_launch(void* const* d_in, const int* in_sizes, int n_in,
                              void* d_out, int out_size, void* d_ws, size_t ws_size,
                              hipStream_t stream)
{
    const float* x       = (const float*)d_in[0];
    const float* past_kv = (const float*)d_in[1];
    const float* Wq      = (const float*)d_in[2];
    const float* bq      = (const float*)d_in[3];
    const float* Wk      = (const float*)d_in[4];
    const float* bk      = (const float*)d_in[5];
    const float* Wv      = (const float*)d_in[6];
    const float* bv      = (const float*)d_in[7];

    float* out = (float*)d_out;                    // [M*64]
    float* ckv = out + (size_t)M * 64;             // [M*4096]

    unsigned short* Wb   = (unsigned short*)d_ws;              // 192*512 bf16
    unsigned short* qkvb = Wb + (size_t)NQKV * E;              // M*192 bf16
    float* partials = (float*)(qkvb + (size_t)M * NQKV);       // NBLKS*2
    float* stats    = partials + (size_t)NBLKS * 2;            // 64

    convw_kernel<<<96, 256, 0, stream>>>(Wq, Wk, Wv, Wb);
    proj_mfma_kernel<<<M / 64, 512, 0, stream>>>(x, Wb, bq, bk, bv, qkvb);
    retention_kernel<<<NBLKS, 512, 0, stream>>>(qkvb, past_kv, out, ckv, partials);
    group_reduce_kernel<<<32, 64, 0, stream>>>(partials, stats);
    normalize_kernel<<<(M * 16) / 256, 256, 0, stream>>>(out, stats);
}